// Round 12
// baseline (132.787 us; speedup 1.0000x reference)
//
#include <hip/hip_runtime.h>
#include <hip/hip_bf16.h>
#include <math.h>
#include <type_traits>

#define B_ 2
#define T_ 2048
#define D_ 1024
#define H_ 16
#define DH_ 64

typedef __bf16 bf16_t;
typedef bf16_t bf16x8 __attribute__((ext_vector_type(8)));
typedef bf16_t bf16x4 __attribute__((ext_vector_type(4)));
typedef float f32x4 __attribute__((ext_vector_type(4)));

typedef __attribute__((address_space(1))) const void gas_void;
typedef __attribute__((address_space(3))) void las_void;

__device__ __forceinline__ void gld16(const void* g, void* l) {
    __builtin_amdgcn_global_load_lds((gas_void*)g, (las_void*)l, 16, 0, 0);
}

#define WAITALL() asm volatile("s_waitcnt vmcnt(0) lgkmcnt(0)" ::: "memory")
#define BARRIER() do { asm volatile("" ::: "memory"); __builtin_amdgcn_s_barrier(); asm volatile("" ::: "memory"); } while (0)

// ------- fused fp32->bf16 convert (x, w_qkv, w_out) + RoPE table -------------
__global__ __launch_bounds__(256) void cvt3(const float* __restrict__ a,
                                            const float* __restrict__ b,
                                            const float* __restrict__ c,
                                            bf16_t* __restrict__ oa,
                                            bf16_t* __restrict__ ob,
                                            bf16_t* __restrict__ oc,
                                            float2* __restrict__ tab) {
    if (blockIdx.x >= 8192) {                         // RoPE table: [2048][32] float2
        int j = (blockIdx.x - 8192) * 256 + threadIdx.x;   // 65536 entries
        int t = j >> 5, d2 = j & 31;
        float invf = exp2f(-(float)d2 * 0.4152410118609203f); // log2(1e4)/32
        float ang = (float)t * invf;
        float sn, cs;
        sincosf(ang, &sn, &cs);
        tab[j] = make_float2(cs, sn);
        return;
    }
    int i = blockIdx.x * 256 + threadIdx.x;          // vec4 index, 2097152 total
    const float* src; bf16_t* dst; int off;
    if (i < 1048576)      { src = a; dst = oa; off = i; }
    else if (i < 1835008) { src = b; dst = ob; off = i - 1048576; }
    else                  { src = c; dst = oc; off = i - 1835008; }
    float4 f = ((const float4*)src)[off];
    bf16x4 v = { (bf16_t)f.x, (bf16_t)f.y, (bf16_t)f.z, (bf16_t)f.w };
    ((bf16x4*)dst)[off] = v;
}

// ---------------- 128x256 GEMM (QKV), BK=32, 8 waves, 384 blocks -------------
__global__ __launch_bounds__(512, 4) void gemmqkv(const bf16_t* __restrict__ A,
                                                  const bf16_t* __restrict__ Bw,
                                                  const float* __restrict__ bias,
                                                  const float2* __restrict__ tab,
                                                  bf16_t* __restrict__ q_out,
                                                  bf16_t* __restrict__ k_out,
                                                  bf16_t* __restrict__ vt_out) {
    __shared__ __align__(16) char smem[65536];   // loop: 2 x 24KB; epilogue: 8 x 8KB

    int tid = threadIdx.x;
    int lane = tid & 63, wid = tid >> 6;
    int wm = wid >> 2, wn = wid & 3;             // wave grid 2M x 4N (64x64 tiles)
    int lr = lane & 15, lk = lane >> 4;

    // XCD bijective chunking: 384 blocks = 8 XCD x 48
    int l = blockIdx.y * 12 + blockIdx.x;
    int u = (l & 7) * 48 + (l >> 3);
    int bx = u % 12;                             // n-tile (256 wide)
    int by = u / 12;                             // m-tile (128 tall)

    f32x4 acc[4][4];
    f32x4 z = {0.f, 0.f, 0.f, 0.f};
#pragma unroll
    for (int i = 0; i < 4; i++)
#pragma unroll
        for (int j = 0; j < 4; j++) acc[i][j] = z;

    // ---- staging: swizzle on global source, LDS dest linear (G21) ----
    int cb = (tid & 3) * 16;                     // in-row byte (64B rows, BK=32)
    int rT = tid >> 2;                           // 0..127
    int sw = cb ^ (((rT >> 1) & 3) << 4);        // involution
    const char* gAp  = (const char*)A  + ((size_t)(by * 128 + rT)) * 2048 + sw;
    const char* gBp0 = (const char*)Bw + ((size_t)(bx * 256 + rT)) * 2048 + sw;
    const char* gBp1 = (const char*)Bw + ((size_t)(bx * 256 + 128 + rT)) * 2048 + sw;

    auto stg = [&](int par, int kt) __attribute__((always_inline)) {
        char* base = smem + par * 24576;
        gld16(gAp  + kt * 64, base + tid * 16);           // A [128][32]
        gld16(gBp0 + kt * 64, base + 8192 + tid * 16);    // B rows 0..127
        gld16(gBp1 + kt * 64, base + 16384 + tid * 16);   // B rows 128..255
    };

    // ---- fragment read offsets (same swizzle) ----
    int offA[4], offB[4];
#pragma unroll
    for (int m = 0; m < 4; m++) {
        int row = wm * 64 + m * 16 + lr;
        offA[m] = row * 64 + ((lk * 16) ^ (((row >> 1) & 3) << 4));
    }
#pragma unroll
    for (int n = 0; n < 4; n++) {
        int row = wn * 64 + n * 16 + lr;
        offB[n] = 8192 + row * 64 + ((lk * 16) ^ (((row >> 1) & 3) << 4));
    }

    stg(0, 0);
    for (int kt = 0; kt < 32; ++kt) {
        const char* buf = smem + (kt & 1) * 24576;
        WAITALL();                 // tile kt landed; own ds_reads of kt-1 done
        BARRIER();                 // all waves agree -> parity (kt+1)&1 free
        if (kt < 31) stg((kt + 1) & 1, kt + 1);
        bf16x8 Af[4], Bf[4];
#pragma unroll
        for (int m = 0; m < 4; m++) Af[m] = *(const bf16x8*)(buf + offA[m]);
#pragma unroll
        for (int n = 0; n < 4; n++) Bf[n] = *(const bf16x8*)(buf + offB[n]);
        __builtin_amdgcn_s_setprio(1);
#pragma unroll
        for (int m = 0; m < 4; m++)
#pragma unroll
            for (int n = 0; n < 4; n++)
                acc[m][n] = __builtin_amdgcn_mfma_f32_16x16x32_bf16(Af[m], Bf[n], acc[m][n], 0, 0, 0);
        __builtin_amdgcn_s_setprio(0);
    }
    WAITALL();
    BARRIER();   // all compute done before smem repurposed

    // ---- epilogue: per-wave 64x64 tile via wave-private 8KB LDS ----
    int m_base = by * 128 + wm * 64;
    int n_base = bx * 256 + wn * 64;
    char* myL = smem + wid * 8192;
    int which = n_base >> 10;               // 0=q 1=k 2=v (uniform per wave)
    int h = (n_base & 1023) >> 6;
    int b = m_base >> 11, t0 = m_base & 2047;
    int bh = b * H_ + h;
    if (which == 2) {
        // stage C^T: row=dh(64), col=t(64), t sigma^-1-permuted in 32-blocks
#pragma unroll
        for (int m = 0; m < 4; m++)
#pragma unroll
            for (int n = 0; n < 4; n++) {
                int rd = n * 16 + lr;
                float bv = bias[n_base + rd];
#pragma unroll
                for (int j = 0; j < 4; j++) {
                    int ct = m * 16 + lk * 4 + j;
                    int ct2 = (ct & 32) | (((ct >> 2) & 3) << 3) | (((ct >> 4) & 1) << 2) | (ct & 3);
                    int addr = (rd * 128 + ct2 * 2) ^ ((rd & 7) << 4);
                    *(bf16_t*)(myL + addr) = (bf16_t)(acc[m][n][j] + bv);
                }
            }
#pragma unroll
        for (int it = 0; it < 8; it++) {
            int row = it * 8 + (lane >> 3);     // dh
            int byt = (lane & 7) * 16;
            bf16x8 val = *(const bf16x8*)(myL + ((row * 128 + byt) ^ ((row & 7) << 4)));
            *(bf16x8*)(vt_out + ((size_t)bh * DH_ + row) * T_ + t0 + (lane & 7) * 8) = val;
        }
    } else {
        bf16_t* dst = which ? k_out : q_out;
        float qscl = which ? 1.0f : 0.18033688011112042f;  // q: fold (1/8)*log2(e)
#pragma unroll
        for (int m = 0; m < 4; m++)
#pragma unroll
            for (int n = 0; n < 4; n++) {
                int dh = n * 16 + lr;
                float bv = bias[n_base + dh];
                int dh2 = dh >> 1;
                bool even = (dh & 1) == 0;
#pragma unroll
                for (int j = 0; j < 4; j++) {
                    int rt = m * 16 + lk * 4 + j;
                    float v = acc[m][n][j] + bv;
                    float pp = __shfl_xor(v, 1);           // partner dh^1 in lane^1
                    float2 cs = tab[(t0 + rt) * 32 + dh2];
                    float r = even ? v * cs.x - pp * cs.y : v * cs.x + pp * cs.y;
                    r *= qscl;
                    int addr = (rt * 128 + dh * 2) ^ ((rt & 7) << 4);
                    *(bf16_t*)(myL + addr) = (bf16_t)r;
                }
            }
#pragma unroll
        for (int it = 0; it < 8; it++) {
            int row = it * 8 + (lane >> 3);     // t_local
            int byt = (lane & 7) * 16;
            bf16x8 val = *(const bf16x8*)(myL + ((row * 128 + byt) ^ ((row & 7) << 4)));
            *(bf16x8*)(dst + ((size_t)bh * T_ + t0 + row) * DH_ + (lane & 7) * 8) = val;
        }
    }
}

// ---------------- 128x128 GEMM (out-proj), 3-deep counted-vmcnt pipeline -----
__global__ __launch_bounds__(256) void gemm128o(const bf16_t* __restrict__ A,
                                                const bf16_t* __restrict__ Bw,
                                                const float* __restrict__ bias,
                                                float* __restrict__ f_out,
                                                int K, int N) {
    __shared__ __align__(16) char smem[49152];
    char* b0 = smem;
    char* b1 = smem + 16384;
    char* b2 = smem + 32768;

    int tid = threadIdx.x;
    int lane = tid & 63, wid = tid >> 6;
    int wr = wid >> 1, wc = wid & 1;
    int lr = lane & 15, lk = lane >> 4;

    int l = blockIdx.y * gridDim.x + blockIdx.x;
    int chunk = (gridDim.x * gridDim.y) >> 3;
    int u = (l & 7) * chunk + (l >> 3);
    int bx = u % gridDim.x;
    int by = u / gridDim.x;

    f32x4 acc[4][4];
    f32x4 z = {0.f, 0.f, 0.f, 0.f};
#pragma unroll
    for (int i = 0; i < 4; i++)
#pragma unroll
        for (int j = 0; j < 4; j++) acc[i][j] = z;

    const char* Ab = (const char*)(A + (size_t)by * 128 * K);
    const char* Bb = (const char*)(Bw + (size_t)bx * 128 * K);
    const int rowstride = K * 2;

    int p0 = tid * 16;
    int p1 = 4096 + tid * 16;
    int r0 = p0 >> 6, r1 = p1 >> 6;
    int cb0 = (p0 & 63) ^ (((r0 >> 1) & 3) << 4);
    int cb1 = (p1 & 63) ^ (((r1 >> 1) & 3) << 4);
    size_t gA0 = (size_t)r0 * rowstride + cb0;
    size_t gA1 = (size_t)r1 * rowstride + cb1;

    int oa[4], ob[4];
#pragma unroll
    for (int m = 0; m < 4; m++) {
        int row = wr * 64 + m * 16 + lr;
        oa[m] = row * 64 + ((lk * 16) ^ (((row >> 1) & 3) << 4));
    }
#pragma unroll
    for (int n = 0; n < 4; n++) {
        int row = wc * 64 + n * 16 + lr;
        ob[n] = row * 64 + ((lk * 16) ^ (((row >> 1) & 3) << 4));
    }

    auto stg = [&](char* buf, int ks) __attribute__((always_inline)) {
        const char* Ag = Ab + (size_t)ks * 64;
        const char* Bg = Bb + (size_t)ks * 64;
        gld16(Ag + gA0, buf + p0);
        gld16(Ag + gA1, buf + p1);
        gld16(Bg + gA0, buf + 8192 + p0);
        gld16(Bg + gA1, buf + 8192 + p1);
    };

    auto iterf = [&](auto vmc, char* buf, int ks, bool dostage) __attribute__((always_inline)) {
        constexpr int VM = decltype(vmc)::value;
        if constexpr (VM == 8)      asm volatile("s_waitcnt vmcnt(8)" ::: "memory");
        else if constexpr (VM == 4) asm volatile("s_waitcnt vmcnt(4)" ::: "memory");
        else                        asm volatile("s_waitcnt vmcnt(0)" ::: "memory");
        __builtin_amdgcn_s_barrier();
        asm volatile("" ::: "memory");
        bf16x8 Af[4], Bf[4];
#pragma unroll
        for (int m = 0; m < 4; m++) Af[m] = *(const bf16x8*)(buf + oa[m]);
#pragma unroll
        for (int n = 0; n < 4; n++) Bf[n] = *(const bf16x8*)(buf + 8192 + ob[n]);
#pragma unroll
        for (int m = 0; m < 4; m++)
#pragma unroll
            for (int n = 0; n < 4; n++)
                acc[m][n] = __builtin_amdgcn_mfma_f32_16x16x32_bf16(Af[m], Bf[n], acc[m][n], 0, 0, 0);
        asm volatile("" ::: "memory");
        __builtin_amdgcn_s_barrier();
        asm volatile("" ::: "memory");
        if (dostage) stg(buf, ks);
    };

    std::integral_constant<int, 8> c8;
    std::integral_constant<int, 4> c4;
    std::integral_constant<int, 0> c0;

    stg(b0, 0);
    stg(b1, 1);
    stg(b2, 2);
    for (int s = 0; s < 30; s += 3) {
        iterf(c8, b0, s + 3, s + 3 < 32);
        iterf(c8, b1, s + 4, s + 4 < 32);
        iterf(c8, b2, s + 5, s + 5 < 32);
    }
    iterf(c4, b0, 0, false);
    iterf(c0, b1, 0, false);

    int m_base = by * 128 + wr * 64;
    int n_base = bx * 128 + wc * 64;
#pragma unroll
    for (int m = 0; m < 4; m++) {
        int gm0 = m_base + m * 16 + lk * 4;
#pragma unroll
        for (int n = 0; n < 4; n++) {
            int nc = n_base + n * 16 + lr;
            float bv = bias[nc];
#pragma unroll
            for (int j = 0; j < 4; j++)
                f_out[(size_t)(gm0 + j) * N + nc] = acc[m][n][j] + bv;
        }
    }
}

// ------- flash attention: BARRIER-FREE 1-wave blocks, 64 q/wave --------------
// 1024 blocks x 64 threads. Each wave owns 64 q rows (4 groups of 16) and a
// private 32KB LDS slice (K ping 2x8K, V ping 2x8K). No s_barrier anywhere:
// the step-top WAITALL (own vmcnt+lgkmcnt) guarantees (a) stage(s) landed,
// (b) own ds_reads of s-1 drained -> staging s+1 is safe single-threaded.
// K/V fragments read once serve 4 groups (4x less LDS traffic per unit work).
// Balanced co-resident 4-tuple: qt mapping makes per-CU tile-sum constant(66).
// No-max softmax (validated r8-r11).
__global__ __launch_bounds__(64, 2) void attnw(const bf16_t* __restrict__ Q,
                                               const bf16_t* __restrict__ K,
                                               const bf16_t* __restrict__ Vt,
                                               bf16_t* __restrict__ Ao) {
    __shared__ __align__(16) char smem[32768];  // K0@0 K1@8K V0@16K V1@24K

    int lane = threadIdx.x;            // 1 wave
    int lr = lane & 15, lk = lane >> 4;
    int bidx = blockIdx.x;
    int xcd = bidx & 7, idx = bidx >> 3;       // idx 0..127
    int bh = xcd * 4 + (idx & 3);
    int q5 = idx >> 2;                 // 0..31
    // co-resident {x, x+8, x+16, x+24} -> qt {x, 15-x, x+16, 31-x}: sum 62 const
    int qt = (q5 < 8) ? q5 : (q5 < 16) ? 23 - q5 : (q5 < 24) ? q5 : 55 - q5;
    int q0 = qt * 64;

    // Q fragments: 4 groups of 16 rows (rows q0 + g*16 + lr)
    const bf16_t* Qp = Q + ((size_t)bh * T_ + q0 + lr) * DH_;
    bf16x8 qf0_0 = *(const bf16x8*)(Qp + 0 * 16 * DH_ + lk * 8);
    bf16x8 qf1_0 = *(const bf16x8*)(Qp + 0 * 16 * DH_ + 32 + lk * 8);
    bf16x8 qf0_1 = *(const bf16x8*)(Qp + 1 * 16 * DH_ + lk * 8);
    bf16x8 qf1_1 = *(const bf16x8*)(Qp + 1 * 16 * DH_ + 32 + lk * 8);
    bf16x8 qf0_2 = *(const bf16x8*)(Qp + 2 * 16 * DH_ + lk * 8);
    bf16x8 qf1_2 = *(const bf16x8*)(Qp + 2 * 16 * DH_ + 32 + lk * 8);
    bf16x8 qf0_3 = *(const bf16x8*)(Qp + 3 * 16 * DH_ + lk * 8);
    bf16x8 qf1_3 = *(const bf16x8*)(Qp + 3 * 16 * DH_ + 32 + lk * 8);

    f32x4 zz = {0.f, 0.f, 0.f, 0.f};
    f32x4 oacc[4][4];                  // [group][dt] O^T: col q=lr, rows dh
#pragma unroll
    for (int g = 0; g < 4; g++)
#pragma unroll
        for (int dt = 0; dt < 4; dt++) oacc[g][dt] = zz;
    float ls[4] = {0.f, 0.f, 0.f, 0.f};
    bf16x8 pf[4][2];                   // P frags per group (static idx only)

    const char* Kbase = (const char*)(K + (size_t)bh * T_ * DH_);
    const char* Vbase = (const char*)(Vt + (size_t)bh * DH_ * T_);

    auto stage = [&](int s) __attribute__((always_inline)) {
        int kv0 = s * 64;
        char* Kd = smem + (s & 1) * 8192;
        char* Vd = smem + 16384 + (s & 1) * 8192;
        const char* Kg = Kbase + (size_t)kv0 * 128;
#pragma unroll
        for (int c = 0; c < 8; c++) {
            int o = c * 1024 + lane * 16;
            int r = o >> 7;
            int g = o ^ ((r & 7) << 4);               // pre-swizzled source
            gld16(Kg + g, Kd + o);
            gld16(Vbase + (size_t)r * (T_ * 2) + kv0 * 2 + (g & 127), Vd + o);
        }
    };

    auto do_qk = [&](const char* Kc, bool dmask) __attribute__((always_inline)) {
#pragma unroll
        for (int kt = 0; kt < 4; kt++) {
            int row = kt * 16 + lr;
            int key = (row & 7) << 4;
            bf16x8 kf0 = *(const bf16x8*)(Kc + ((row * 128 + lk * 16) ^ key));
            bf16x8 kf1 = *(const bf16x8*)(Kc + ((row * 128 + 64 + lk * 16) ^ key));
#pragma unroll
            for (int g = 0; g < 4; g++) {
                f32x4 s = zz;
                bf16x8 qa = (g == 0) ? qf0_0 : (g == 1) ? qf0_1 : (g == 2) ? qf0_2 : qf0_3;
                bf16x8 qb = (g == 0) ? qf1_0 : (g == 1) ? qf1_1 : (g == 2) ? qf1_2 : qf1_3;
                s = __builtin_amdgcn_mfma_f32_16x16x32_bf16(kf0, qa, s, 0, 0, 0);
                s = __builtin_amdgcn_mfma_f32_16x16x32_bf16(kf1, qb, s, 0, 0, 0);
#pragma unroll
                for (int j = 0; j < 4; j++) {
                    float sv = s[j];
                    if (dmask) {
                        int kv = kt * 16 + lk * 4 + j;
                        sv = (kv <= g * 16 + lr) ? sv : -__builtin_inff();
                    }
                    float e = exp2f(sv);
                    ls[g] += e;
                    pf[g][kt >> 1][(kt & 1) * 4 + j] = (bf16_t)e;
                }
            }
        }
    };

    auto do_pv = [&](const char* Vc) __attribute__((always_inline)) {
#pragma unroll
        for (int dt = 0; dt < 4; dt++) {
            int row = dt * 16 + lr;
            int key = (row & 7) << 4;
            bf16x8 vf0 = *(const bf16x8*)(Vc + ((row * 128 + lk * 16) ^ key));
            bf16x8 vf1 = *(const bf16x8*)(Vc + ((row * 128 + 64 + lk * 16) ^ key));
#pragma unroll
            for (int g = 0; g < 4; g++) {
                f32x4 o = oacc[g][dt];
                o = __builtin_amdgcn_mfma_f32_16x16x32_bf16(vf0, pf[g][0], o, 0, 0, 0);
                o = __builtin_amdgcn_mfma_f32_16x16x32_bf16(vf1, pf[g][1], o, 0, 0, 0);
                oacc[g][dt] = o;
            }
        }
    };

    // ---- main stream: tiles 0..qt, fully self-paced ----
    stage(0);
    for (int s = 0; s <= qt; ++s) {
        WAITALL();                     // own stage(s) landed; own ds_reads of s-1 done
        if (s < qt) stage(s + 1);      // overwrites s-1 parity: safe (reads drained)
        const char* Kc = smem + (s & 1) * 8192;
        const char* Vc = smem + 16384 + (s & 1) * 8192;
        do_qk(Kc, s == qt);
        do_pv(Vc);
    }
    asm volatile("s_waitcnt lgkmcnt(0)" ::: "memory");   // reads done before reuse

    // ---- output: per group, stage [16q][64dh] in 2KB then 128B-row stores ----
    int bb = bh >> 4, hh = bh & 15;
#pragma unroll
    for (int g = 0; g < 4; g++) {
        float l = ls[g];
        l += __shfl_xor(l, 16);
        l += __shfl_xor(l, 32);
        float ri = __builtin_amdgcn_rcpf(l);
#pragma unroll
        for (int dt = 0; dt < 4; dt++)
#pragma unroll
            for (int j = 0; j < 4; j++) {
                int dh = dt * 16 + lk * 4 + j;
                int addr = (lr * 128 + dh * 2) ^ ((lr & 7) << 4);
                *(bf16_t*)(smem + addr) = (bf16_t)(oacc[g][dt][j] * ri);
            }
#pragma unroll
        for (int it = 0; it < 2; it++) {
            int row = it * 8 + (lane >> 3);
            int byt = (lane & 7) * 16;
            bf16x8 val = *(const bf16x8*)(smem + ((row * 128 + byt) ^ ((row & 7) << 4)));
            int t = q0 + g * 16 + row;
            *(bf16x8*)(Ao + ((size_t)bb * T_ + t) * D_ + hh * DH_ + (lane & 7) * 8) = val;
        }
    }
}

// ---------------- launch ----------------
extern "C" void kernel_launch(void* const* d_in, const int* in_sizes, int n_in,
                              void* d_out, int out_size, void* d_ws, size_t ws_size,
                              hipStream_t stream) {
    const float* x     = (const float*)d_in[0];
    const float* w_qkv = (const float*)d_in[1];
    const float* b_qkv = (const float*)d_in[2];
    const float* w_out = (const float*)d_in[3];
    const float* b_out = (const float*)d_in[4];
    float* out = (float*)d_out;

    char* ws = (char*)d_ws;
    bf16_t* xb    = (bf16_t*)(ws);               //  8 MB  [4096][1024]
    bf16_t* wqkvb = (bf16_t*)(ws + 8388608);     //  6 MB  [3072][1024]
    bf16_t* wob   = (bf16_t*)(ws + 14680064);    //  2 MB  [1024][1024]
    bf16_t* qb    = (bf16_t*)(ws + 16777216);    //  8 MB  [32][2048][64] (pre-scaled)
    bf16_t* kb    = (bf16_t*)(ws + 25165824);    //  8 MB  [32][2048][64]
    bf16_t* vtb   = (bf16_t*)(ws + 33554432);    //  8 MB  [32][64][2048] (sigma-permuted t)
    bf16_t* ab    = (bf16_t*)(ws + 41943040);    //  8 MB  [4096][1024]
    float2* tab   = (float2*)(ws + 41943040);    // 512 KB RoPE table, lives in ab region

    cvt3<<<8448, 256, 0, stream>>>(x, w_qkv, w_out, xb, wqkvb, wob, tab);

    gemmqkv<<<dim3(12, 32), 512, 0, stream>>>(xb, wqkvb, b_qkv, tab, qb, kb, vtb);
    attnw<<<1024, 64, 0, stream>>>(qb, kb, vtb, ab);
    gemm128o<<<dim3(8, 32), 256, 0, stream>>>(ab, wob, b_out, out, 1024, 1024);
}

// Round 13
// 111.265 us; speedup vs baseline: 1.1934x; 1.1934x over previous
//
#include <hip/hip_runtime.h>
#include <hip/hip_bf16.h>
#include <math.h>
#include <type_traits>

#define B_ 2
#define T_ 2048
#define D_ 1024
#define H_ 16
#define DH_ 64

typedef __bf16 bf16_t;
typedef bf16_t bf16x8 __attribute__((ext_vector_type(8)));
typedef bf16_t bf16x4 __attribute__((ext_vector_type(4)));
typedef float f32x4 __attribute__((ext_vector_type(4)));

typedef __attribute__((address_space(1))) const void gas_void;
typedef __attribute__((address_space(3))) void las_void;

__device__ __forceinline__ void gld16(const void* g, void* l) {
    __builtin_amdgcn_global_load_lds((gas_void*)g, (las_void*)l, 16, 0, 0);
}

#define WAITALL() asm volatile("s_waitcnt vmcnt(0) lgkmcnt(0)" ::: "memory")
#define BARRIER() do { asm volatile("" ::: "memory"); __builtin_amdgcn_s_barrier(); asm volatile("" ::: "memory"); } while (0)

// ------- fused fp32->bf16 convert (x, w_qkv, w_out) + RoPE table -------------
__global__ __launch_bounds__(256) void cvt3(const float* __restrict__ a,
                                            const float* __restrict__ b,
                                            const float* __restrict__ c,
                                            bf16_t* __restrict__ oa,
                                            bf16_t* __restrict__ ob,
                                            bf16_t* __restrict__ oc,
                                            float2* __restrict__ tab) {
    if (blockIdx.x >= 8192) {                         // RoPE table: [2048][32] float2
        int j = (blockIdx.x - 8192) * 256 + threadIdx.x;   // 65536 entries
        int t = j >> 5, d2 = j & 31;
        float invf = exp2f(-(float)d2 * 0.4152410118609203f); // log2(1e4)/32
        float ang = (float)t * invf;
        float sn, cs;
        sincosf(ang, &sn, &cs);
        tab[j] = make_float2(cs, sn);
        return;
    }
    int i = blockIdx.x * 256 + threadIdx.x;          // vec4 index, 2097152 total
    const float* src; bf16_t* dst; int off;
    if (i < 1048576)      { src = a; dst = oa; off = i; }
    else if (i < 1835008) { src = b; dst = ob; off = i - 1048576; }
    else                  { src = c; dst = oc; off = i - 1835008; }
    float4 f = ((const float4*)src)[off];
    bf16x4 v = { (bf16_t)f.x, (bf16_t)f.y, (bf16_t)f.z, (bf16_t)f.w };
    ((bf16x4*)dst)[off] = v;
}

// ------- 128x128 GEMM (QKV), BK=32, 4 waves, 768 blocks = exactly 3/CU -------
// r8's relaxed structure: ONE vmcnt(0)+lgkmcnt(0)+barrier per K-step, next
// step staged right after; 2-parity 32KB LDS -> 3 blocks resident (grid-exact).
// Epilogue: RoPE(q,k) -> q[BH][T][64] (q pre-scaled log2e/8), k[BH][T][64],
//           vT[BH][64][T] with sigma^-1-permuted t (matches attn's P k-slots).
__global__ __launch_bounds__(256, 3) void gemmqkv(const bf16_t* __restrict__ A,
                                                  const bf16_t* __restrict__ Bw,
                                                  const float* __restrict__ bias,
                                                  const float2* __restrict__ tab,
                                                  bf16_t* __restrict__ q_out,
                                                  bf16_t* __restrict__ k_out,
                                                  bf16_t* __restrict__ vt_out) {
    __shared__ __align__(16) char smem[32768];   // 2 parities x (A 8KB + B 8KB)

    int tid = threadIdx.x;
    int lane = tid & 63, wid = tid >> 6;
    int wr = wid >> 1, wc = wid & 1;             // wave grid 2x2, 64x64 tiles
    int lr = lane & 15, lk = lane >> 4;

    // XCD bijective chunking: 768 blocks = 8 XCD x 96
    int l = blockIdx.y * 24 + blockIdx.x;
    int u = (l & 7) * 96 + (l >> 3);
    int bx = u % 24;                             // n-tile (128 wide, 24 tiles)
    int by = u / 24;                             // m-tile (128 tall, 32 tiles)

    f32x4 acc[4][4];
    f32x4 z = {0.f, 0.f, 0.f, 0.f};
#pragma unroll
    for (int i = 0; i < 4; i++)
#pragma unroll
        for (int j = 0; j < 4; j++) acc[i][j] = z;

    // ---- staging: swizzle on global source, LDS dest linear (G21) ----
    int cb = (tid & 3) * 16;                     // in-row byte (64B rows, BK=32)
    int rT = tid >> 2;                           // rows 0..63; slot1 = +64
    int sw = cb ^ (((rT >> 1) & 3) << 4);        // involution (row-parity safe: 64%8==0)
    const char* gAp  = (const char*)A  + ((size_t)(by * 128 + rT)) * 2048 + sw;
    const char* gAp1 = gAp + (size_t)64 * 2048;
    const char* gBp  = (const char*)Bw + ((size_t)(bx * 128 + rT)) * 2048 + sw;
    const char* gBp1 = gBp + (size_t)64 * 2048;

    auto stg = [&](int par, int kt) __attribute__((always_inline)) {
        char* base = smem + par * 16384;
        gld16(gAp  + kt * 64, base + tid * 16);           // A rows 0..63
        gld16(gAp1 + kt * 64, base + 4096 + tid * 16);    // A rows 64..127
        gld16(gBp  + kt * 64, base + 8192 + tid * 16);    // B rows 0..63
        gld16(gBp1 + kt * 64, base + 12288 + tid * 16);   // B rows 64..127
    };

    // ---- fragment read offsets (same swizzle) ----
    int offA[4], offB[4];
#pragma unroll
    for (int m = 0; m < 4; m++) {
        int row = wr * 64 + m * 16 + lr;
        offA[m] = row * 64 + ((lk * 16) ^ (((row >> 1) & 3) << 4));
    }
#pragma unroll
    for (int n = 0; n < 4; n++) {
        int row = wc * 64 + n * 16 + lr;
        offB[n] = 8192 + row * 64 + ((lk * 16) ^ (((row >> 1) & 3) << 4));
    }

    stg(0, 0);
    for (int kt = 0; kt < 32; ++kt) {
        const char* buf = smem + (kt & 1) * 16384;
        WAITALL();                 // tile kt landed; own ds_reads of kt-1 done
        BARRIER();                 // all waves agree -> parity (kt+1)&1 free
        if (kt < 31) stg((kt + 1) & 1, kt + 1);
        bf16x8 Af[4], Bf[4];
#pragma unroll
        for (int m = 0; m < 4; m++) Af[m] = *(const bf16x8*)(buf + offA[m]);
#pragma unroll
        for (int n = 0; n < 4; n++) Bf[n] = *(const bf16x8*)(buf + offB[n]);
        __builtin_amdgcn_s_setprio(1);
#pragma unroll
        for (int m = 0; m < 4; m++)
#pragma unroll
            for (int n = 0; n < 4; n++)
                acc[m][n] = __builtin_amdgcn_mfma_f32_16x16x32_bf16(Af[m], Bf[n], acc[m][n], 0, 0, 0);
        __builtin_amdgcn_s_setprio(0);
    }
    WAITALL();
    BARRIER();   // all compute done before smem repurposed

    // ---- epilogue: per-wave 64x64 tile via wave-private 8KB LDS ----
    int m_base = by * 128 + wr * 64;
    int n_base = bx * 128 + wc * 64;
    char* myL = smem + wid * 8192;
    int which = n_base >> 10;               // 0=q 1=k 2=v (uniform per wave)
    int h = (n_base & 1023) >> 6;
    int b = m_base >> 11, t0 = m_base & 2047;
    int bh = b * H_ + h;
    if (which == 2) {
        // stage C^T: row=dh(64), col=t(64), t sigma^-1-permuted in 32-blocks
#pragma unroll
        for (int m = 0; m < 4; m++)
#pragma unroll
            for (int n = 0; n < 4; n++) {
                int rd = n * 16 + lr;
                float bv = bias[n_base + rd];
#pragma unroll
                for (int j = 0; j < 4; j++) {
                    int ct = m * 16 + lk * 4 + j;
                    int ct2 = (ct & 32) | (((ct >> 2) & 3) << 3) | (((ct >> 4) & 1) << 2) | (ct & 3);
                    int addr = (rd * 128 + ct2 * 2) ^ ((rd & 7) << 4);
                    *(bf16_t*)(myL + addr) = (bf16_t)(acc[m][n][j] + bv);
                }
            }
#pragma unroll
        for (int it = 0; it < 8; it++) {
            int row = it * 8 + (lane >> 3);     // dh
            int byt = (lane & 7) * 16;
            bf16x8 val = *(const bf16x8*)(myL + ((row * 128 + byt) ^ ((row & 7) << 4)));
            *(bf16x8*)(vt_out + ((size_t)bh * DH_ + row) * T_ + t0 + (lane & 7) * 8) = val;
        }
    } else {
        bf16_t* dst = which ? k_out : q_out;
        float qscl = which ? 1.0f : 0.18033688011112042f;  // q: fold (1/8)*log2(e)
#pragma unroll
        for (int m = 0; m < 4; m++)
#pragma unroll
            for (int n = 0; n < 4; n++) {
                int dh = n * 16 + lr;
                float bv = bias[n_base + dh];
                int dh2 = dh >> 1;
                bool even = (dh & 1) == 0;
#pragma unroll
                for (int j = 0; j < 4; j++) {
                    int rt = m * 16 + lk * 4 + j;
                    float v = acc[m][n][j] + bv;
                    float pp = __shfl_xor(v, 1);           // partner dh^1 in lane^1
                    float2 cs = tab[(t0 + rt) * 32 + dh2];
                    float r = even ? v * cs.x - pp * cs.y : v * cs.x + pp * cs.y;
                    r *= qscl;
                    int addr = (rt * 128 + dh * 2) ^ ((rt & 7) << 4);
                    *(bf16_t*)(myL + addr) = (bf16_t)r;
                }
            }
#pragma unroll
        for (int it = 0; it < 8; it++) {
            int row = it * 8 + (lane >> 3);     // t_local
            int byt = (lane & 7) * 16;
            bf16x8 val = *(const bf16x8*)(myL + ((row * 128 + byt) ^ ((row & 7) << 4)));
            *(bf16x8*)(dst + ((size_t)bh * T_ + t0 + row) * DH_ + (lane & 7) * 8) = val;
        }
    }
}

// ---------------- 128x128 GEMM (out-proj), 3-deep counted-vmcnt pipeline -----
__global__ __launch_bounds__(256) void gemm128o(const bf16_t* __restrict__ A,
                                                const bf16_t* __restrict__ Bw,
                                                const float* __restrict__ bias,
                                                float* __restrict__ f_out,
                                                int K, int N) {
    __shared__ __align__(16) char smem[49152];
    char* b0 = smem;
    char* b1 = smem + 16384;
    char* b2 = smem + 32768;

    int tid = threadIdx.x;
    int lane = tid & 63, wid = tid >> 6;
    int wr = wid >> 1, wc = wid & 1;
    int lr = lane & 15, lk = lane >> 4;

    int l = blockIdx.y * gridDim.x + blockIdx.x;
    int chunk = (gridDim.x * gridDim.y) >> 3;
    int u = (l & 7) * chunk + (l >> 3);
    int bx = u % gridDim.x;
    int by = u / gridDim.x;

    f32x4 acc[4][4];
    f32x4 z = {0.f, 0.f, 0.f, 0.f};
#pragma unroll
    for (int i = 0; i < 4; i++)
#pragma unroll
        for (int j = 0; j < 4; j++) acc[i][j] = z;

    const char* Ab = (const char*)(A + (size_t)by * 128 * K);
    const char* Bb = (const char*)(Bw + (size_t)bx * 128 * K);
    const int rowstride = K * 2;

    int p0 = tid * 16;
    int p1 = 4096 + tid * 16;
    int r0 = p0 >> 6, r1 = p1 >> 6;
    int cb0 = (p0 & 63) ^ (((r0 >> 1) & 3) << 4);
    int cb1 = (p1 & 63) ^ (((r1 >> 1) & 3) << 4);
    size_t gA0 = (size_t)r0 * rowstride + cb0;
    size_t gA1 = (size_t)r1 * rowstride + cb1;

    int oa[4], ob[4];
#pragma unroll
    for (int m = 0; m < 4; m++) {
        int row = wr * 64 + m * 16 + lr;
        oa[m] = row * 64 + ((lk * 16) ^ (((row >> 1) & 3) << 4));
    }
#pragma unroll
    for (int n = 0; n < 4; n++) {
        int row = wc * 64 + n * 16 + lr;
        ob[n] = row * 64 + ((lk * 16) ^ (((row >> 1) & 3) << 4));
    }

    auto stg = [&](char* buf, int ks) __attribute__((always_inline)) {
        const char* Ag = Ab + (size_t)ks * 64;
        const char* Bg = Bb + (size_t)ks * 64;
        gld16(Ag + gA0, buf + p0);
        gld16(Ag + gA1, buf + p1);
        gld16(Bg + gA0, buf + 8192 + p0);
        gld16(Bg + gA1, buf + 8192 + p1);
    };

    auto iterf = [&](auto vmc, char* buf, int ks, bool dostage) __attribute__((always_inline)) {
        constexpr int VM = decltype(vmc)::value;
        if constexpr (VM == 8)      asm volatile("s_waitcnt vmcnt(8)" ::: "memory");
        else if constexpr (VM == 4) asm volatile("s_waitcnt vmcnt(4)" ::: "memory");
        else                        asm volatile("s_waitcnt vmcnt(0)" ::: "memory");
        __builtin_amdgcn_s_barrier();
        asm volatile("" ::: "memory");
        bf16x8 Af[4], Bf[4];
#pragma unroll
        for (int m = 0; m < 4; m++) Af[m] = *(const bf16x8*)(buf + oa[m]);
#pragma unroll
        for (int n = 0; n < 4; n++) Bf[n] = *(const bf16x8*)(buf + 8192 + ob[n]);
#pragma unroll
        for (int m = 0; m < 4; m++)
#pragma unroll
            for (int n = 0; n < 4; n++)
                acc[m][n] = __builtin_amdgcn_mfma_f32_16x16x32_bf16(Af[m], Bf[n], acc[m][n], 0, 0, 0);
        asm volatile("" ::: "memory");
        __builtin_amdgcn_s_barrier();
        asm volatile("" ::: "memory");
        if (dostage) stg(buf, ks);
    };

    std::integral_constant<int, 8> c8;
    std::integral_constant<int, 4> c4;
    std::integral_constant<int, 0> c0;

    stg(b0, 0);
    stg(b1, 1);
    stg(b2, 2);
    for (int s = 0; s < 30; s += 3) {
        iterf(c8, b0, s + 3, s + 3 < 32);
        iterf(c8, b1, s + 4, s + 4 < 32);
        iterf(c8, b2, s + 5, s + 5 < 32);
    }
    iterf(c4, b0, 0, false);
    iterf(c0, b1, 0, false);

    int m_base = by * 128 + wr * 64;
    int n_base = bx * 128 + wc * 64;
#pragma unroll
    for (int m = 0; m < 4; m++) {
        int gm0 = m_base + m * 16 + lk * 4;
#pragma unroll
        for (int n = 0; n < 4; n++) {
            int nc = n_base + n * 16 + lr;
            float bv = bias[nc];
#pragma unroll
            for (int j = 0; j < 4; j++)
                f_out[(size_t)(gm0 + j) * N + nc] = acc[m][n][j] + bv;
        }
    }
}

// ------- flash attention: 128 q/block (2 groups/wave), no-max softmax --------
// (r9 kernel verbatim — best measured attn at 50 us.)
__global__ __launch_bounds__(256, 4) void attn128(const bf16_t* __restrict__ Q,
                                                  const bf16_t* __restrict__ K,
                                                  const bf16_t* __restrict__ Vt,
                                                  bf16_t* __restrict__ Ao) {
    __shared__ __align__(16) char smem[40960];  // K0@0 K1@8K V0@16K V1@24K V2@32K

    int tid = threadIdx.x;
    int lane = tid & 63, wid = tid >> 6;
    int lr = lane & 15, lk = lane >> 4;
    int xcd = blockIdx.x & 7, idx = blockIdx.x >> 3;
    int bh = xcd * 4 + (idx & 3);
    int i4 = idx >> 2;                 // 0..15
    int qt = (i4 < 8) ? i4 : 23 - i4;  // pairs sum to 15 -> per-CU work constant
    int q0 = qt * 128;
    int qrelw = wid * 16 + lr;         // q row within its group

    const bf16_t* Qp0 = Q + ((size_t)bh * T_ + q0 + qrelw) * DH_;
    const bf16_t* Qp1 = Qp0 + 64 * DH_;
    bf16x8 qa0 = *(const bf16x8*)(Qp0 + lk * 8);       // group0
    bf16x8 qa1 = *(const bf16x8*)(Qp0 + 32 + lk * 8);
    bf16x8 qb0 = *(const bf16x8*)(Qp1 + lk * 8);       // group1
    bf16x8 qb1 = *(const bf16x8*)(Qp1 + 32 + lk * 8);

    f32x4 zz = {0.f, 0.f, 0.f, 0.f};
    f32x4 oa0[4], oa1[4];              // O^T per group: col q=lr, rows dh
#pragma unroll
    for (int dt = 0; dt < 4; dt++) { oa0[dt] = zz; oa1[dt] = zz; }
    float ls0 = 0.f, ls1 = 0.f;        // per-lane partial row-sums
    bf16x8 pA0, pA1, pB0, pB1;         // current P fragments (g0, g1)

    const char* Kbase = (const char*)(K + (size_t)bh * T_ * DH_);
    const char* Vbase = (const char*)(Vt + (size_t)bh * DH_ * T_);

    auto stage = [&](int s, char* Kd, char* Vd) __attribute__((always_inline)) {
        int kv0 = s * 64;
        const char* Kg = Kbase + (size_t)kv0 * 128;
#pragma unroll
        for (int c = 0; c < 2; c++) {
            int o = c * 4096 + tid * 16;
            int r = o >> 7;
            int g = o ^ ((r & 7) << 4);               // pre-swizzled source
            gld16(Kg + g, Kd + o);
            gld16(Vbase + (size_t)r * (T_ * 2) + kv0 * 2 + (g & 127), Vd + o);
        }
    };

    auto do_qk = [&](const char* Kc, int m0, int m1) __attribute__((always_inline)) {
#pragma unroll
        for (int kt = 0; kt < 4; kt++) {
            int row = kt * 16 + lr;
            int key = (row & 7) << 4;
            bf16x8 kf0 = *(const bf16x8*)(Kc + ((row * 128 + lk * 16) ^ key));
            bf16x8 kf1 = *(const bf16x8*)(Kc + ((row * 128 + 64 + lk * 16) ^ key));
            if (m0 != 2) {
                f32x4 s = zz;
                s = __builtin_amdgcn_mfma_f32_16x16x32_bf16(kf0, qa0, s, 0, 0, 0);
                s = __builtin_amdgcn_mfma_f32_16x16x32_bf16(kf1, qa1, s, 0, 0, 0);
#pragma unroll
                for (int j = 0; j < 4; j++) {
                    float sv = s[j];
                    if (m0 == 1) {
                        int kv = kt * 16 + lk * 4 + j;
                        sv = (kv <= qrelw) ? sv : -__builtin_inff();
                    }
                    float e = exp2f(sv);
                    ls0 += e;
                    if (kt < 2) pA0[kt * 4 + j] = (bf16_t)e;
                    else        pA1[(kt - 2) * 4 + j] = (bf16_t)e;
                }
            }
            {
                f32x4 s = zz;
                s = __builtin_amdgcn_mfma_f32_16x16x32_bf16(kf0, qb0, s, 0, 0, 0);
                s = __builtin_amdgcn_mfma_f32_16x16x32_bf16(kf1, qb1, s, 0, 0, 0);
#pragma unroll
                for (int j = 0; j < 4; j++) {
                    float sv = s[j];
                    if (m1 == 1) {
                        int kv = kt * 16 + lk * 4 + j;
                        sv = (kv <= qrelw) ? sv : -__builtin_inff();
                    }
                    float e = exp2f(sv);
                    ls1 += e;
                    if (kt < 2) pB0[kt * 4 + j] = (bf16_t)e;
                    else        pB1[(kt - 2) * 4 + j] = (bf16_t)e;
                }
            }
        }
    };

    auto do_pv = [&](const char* Vc, bool g0on) __attribute__((always_inline)) {
#pragma unroll
        for (int dt = 0; dt < 4; dt++) {
            int row = dt * 16 + lr;
            int key = (row & 7) << 4;
            bf16x8 vf0 = *(const bf16x8*)(Vc + ((row * 128 + lk * 16) ^ key));
            bf16x8 vf1 = *(const bf16x8*)(Vc + ((row * 128 + 64 + lk * 16) ^ key));
            if (g0on) {
                f32x4 o = oa0[dt];
                o = __builtin_amdgcn_mfma_f32_16x16x32_bf16(vf0, pA0, o, 0, 0, 0);
                o = __builtin_amdgcn_mfma_f32_16x16x32_bf16(vf1, pA1, o, 0, 0, 0);
                oa0[dt] = o;
            }
            f32x4 o = oa1[dt];
            o = __builtin_amdgcn_mfma_f32_16x16x32_bf16(vf0, pB0, o, 0, 0, 0);
            o = __builtin_amdgcn_mfma_f32_16x16x32_bf16(vf1, pB1, o, 0, 0, 0);
            oa1[dt] = o;
        }
    };

    stage(0, smem, smem + 16384);
    stage(1, smem + 8192, smem + 24576);
    asm volatile("s_waitcnt vmcnt(4)" ::: "memory");   // tile 0 landed
    __builtin_amdgcn_s_barrier();
    asm volatile("" ::: "memory");
    do_qk(smem, qt == 0 ? 1 : 0, 0);                   // tile 0: g0 diag iff qt==0

    char* Kr = smem + 8192;            // K(s+1)
    char* Kw = smem;
    char* Vr = smem + 16384;           // V(s)
    char* Vn = smem + 24576;           // V(s+1)
    char* Vw = smem + 32768;

    int last = 2 * qt;                 // final iter index; tiles 0..2qt+1
    auto iterA = [&](int s, int m0, int m1) __attribute__((always_inline)) {
        WAITALL();                     // tile s+1 landed; own reads of s-1 done
        __builtin_amdgcn_s_barrier();
        asm volatile("" ::: "memory");
        if (s + 2 <= last + 1) stage(s + 2, Kw, Vw);
        do_pv(Vr, true);               // PV(s) with current P
        do_qk(Kr, m0, m1);             // QK(s+1), overwrites P
        char* t;
        t = Kr; Kr = Kw; Kw = t;
        t = Vr; Vr = Vn; Vn = Vw; Vw = t;
    };

    for (int s = 0; s < last - 1; ++s) iterA(s, 0, 0);
    if (qt > 0) iterA(last - 1, 1, 0);  // QK(2qt): g0 diagonal
    iterA(last, 2, 1);                  // QK(2qt+1): g0 skip, g1 diagonal
    do_pv(Vr, false);                   // final PV(2qt+1), g1 only
    __syncthreads();                    // smem about to be repurposed

    ls0 += __shfl_xor(ls0, 16); ls0 += __shfl_xor(ls0, 32);
    ls1 += __shfl_xor(ls1, 16); ls1 += __shfl_xor(ls1, 32);
    float ri0 = __builtin_amdgcn_rcpf(ls0);
    float ri1 = __builtin_amdgcn_rcpf(ls1);

    char* myL = smem + wid * 2048;
    int b = bh >> 4, h = bh & 15;
#pragma unroll
    for (int dt = 0; dt < 4; dt++)
#pragma unroll
        for (int j = 0; j < 4; j++) {
            int dh = dt * 16 + lk * 4 + j;
            int addr = (lr * 128 + dh * 2) ^ ((lr & 7) << 4);
            *(bf16_t*)(myL + addr) = (bf16_t)(oa0[dt][j] * ri0);
        }
#pragma unroll
    for (int it = 0; it < 2; it++) {
        int row = it * 8 + (lane >> 3);
        int byt = (lane & 7) * 16;
        bf16x8 val = *(const bf16x8*)(myL + ((row * 128 + byt) ^ ((row & 7) << 4)));
        int t = q0 + wid * 16 + row;
        *(bf16x8*)(Ao + ((size_t)b * T_ + t) * D_ + h * DH_ + (lane & 7) * 8) = val;
    }
#pragma unroll
    for (int dt = 0; dt < 4; dt++)
#pragma unroll
        for (int j = 0; j < 4; j++) {
            int dh = dt * 16 + lk * 4 + j;
            int addr = (lr * 128 + dh * 2) ^ ((lr & 7) << 4);
            *(bf16_t*)(myL + addr) = (bf16_t)(oa1[dt][j] * ri1);
        }
#pragma unroll
    for (int it = 0; it < 2; it++) {
        int row = it * 8 + (lane >> 3);
        int byt = (lane & 7) * 16;
        bf16x8 val = *(const bf16x8*)(myL + ((row * 128 + byt) ^ ((row & 7) << 4)));
        int t = q0 + 64 + wid * 16 + row;
        *(bf16x8*)(Ao + ((size_t)b * T_ + t) * D_ + h * DH_ + (lane & 7) * 8) = val;
    }
}

// ---------------- launch ----------------
extern "C" void kernel_launch(void* const* d_in, const int* in_sizes, int n_in,
                              void* d_out, int out_size, void* d_ws, size_t ws_size,
                              hipStream_t stream) {
    const float* x     = (const float*)d_in[0];
    const float* w_qkv = (const float*)d_in[1];
    const float* b_qkv = (const float*)d_in[2];
    const float* w_out = (const float*)d_in[3];
    const float* b_out = (const float*)d_in[4];
    float* out = (float*)d_out;

    char* ws = (char*)d_ws;
    bf16_t* xb    = (bf16_t*)(ws);               //  8 MB  [4096][1024]
    bf16_t* wqkvb = (bf16_t*)(ws + 8388608);     //  6 MB  [3072][1024]
    bf16_t* wob   = (bf16_t*)(ws + 14680064);    //  2 MB  [1024][1024]
    bf16_t* qb    = (bf16_t*)(ws + 16777216);    //  8 MB  [32][2048][64] (pre-scaled)
    bf16_t* kb    = (bf16_t*)(ws + 25165824);    //  8 MB  [32][2048][64]
    bf16_t* vtb   = (bf16_t*)(ws + 33554432);    //  8 MB  [32][64][2048] (sigma-permuted t)
    bf16_t* ab    = (bf16_t*)(ws + 41943040);    //  8 MB  [4096][1024]
    float2* tab   = (float2*)(ws + 41943040);    // 512 KB RoPE table, lives in ab region

    cvt3<<<8448, 256, 0, stream>>>(x, w_qkv, w_out, xb, wqkvb, wob, tab);

    gemmqkv<<<dim3(24, 32), 256, 0, stream>>>(xb, wqkvb, b_qkv, tab, qb, kb, vtb);
    attn128<<<512, 256, 0, stream>>>(qb, kb, vtb, ab);
    gemm128o<<<dim3(8, 32), 256, 0, stream>>>(ab, wob, b_out, out, 1024, 1024);
}

// Round 14
// 105.627 us; speedup vs baseline: 1.2571x; 1.0534x over previous
//
#include <hip/hip_runtime.h>
#include <hip/hip_bf16.h>
#include <math.h>
#include <type_traits>

#define B_ 2
#define T_ 2048
#define D_ 1024
#define H_ 16
#define DH_ 64

typedef __bf16 bf16_t;
typedef bf16_t bf16x8 __attribute__((ext_vector_type(8)));
typedef bf16_t bf16x4 __attribute__((ext_vector_type(4)));
typedef float f32x4 __attribute__((ext_vector_type(4)));

typedef __attribute__((address_space(1))) const void gas_void;
typedef __attribute__((address_space(3))) void las_void;

__device__ __forceinline__ void gld16(const void* g, void* l) {
    __builtin_amdgcn_global_load_lds((gas_void*)g, (las_void*)l, 16, 0, 0);
}

#define WAITALL() asm volatile("s_waitcnt vmcnt(0) lgkmcnt(0)" ::: "memory")
#define BARRIER() do { asm volatile("" ::: "memory"); __builtin_amdgcn_s_barrier(); asm volatile("" ::: "memory"); } while (0)

// ------- fused fp32->bf16 convert (x, w_qkv, w_out) + RoPE table -------------
__global__ __launch_bounds__(256) void cvt3(const float* __restrict__ a,
                                            const float* __restrict__ b,
                                            const float* __restrict__ c,
                                            bf16_t* __restrict__ oa,
                                            bf16_t* __restrict__ ob,
                                            bf16_t* __restrict__ oc,
                                            float2* __restrict__ tab) {
    if (blockIdx.x >= 8192) {                         // RoPE table: [2048][32] float2
        int j = (blockIdx.x - 8192) * 256 + threadIdx.x;   // 65536 entries
        int t = j >> 5, d2 = j & 31;
        float invf = exp2f(-(float)d2 * 0.4152410118609203f); // log2(1e4)/32
        float ang = (float)t * invf;
        float sn, cs;
        sincosf(ang, &sn, &cs);
        tab[j] = make_float2(cs, sn);
        return;
    }
    int i = blockIdx.x * 256 + threadIdx.x;          // vec4 index, 2097152 total
    const float* src; bf16_t* dst; int off;
    if (i < 1048576)      { src = a; dst = oa; off = i; }
    else if (i < 1835008) { src = b; dst = ob; off = i - 1048576; }
    else                  { src = c; dst = oc; off = i - 1835008; }
    float4 f = ((const float4*)src)[off];
    bf16x4 v = { (bf16_t)f.x, (bf16_t)f.y, (bf16_t)f.z, (bf16_t)f.w };
    ((bf16x4*)dst)[off] = v;
}

// ---------------- 128x256 GEMM (QKV), BK=32, 8 waves, 384 blocks -------------
// (r8/r9 version — best measured ~36 us.)
__global__ __launch_bounds__(512, 4) void gemmqkv(const bf16_t* __restrict__ A,
                                                  const bf16_t* __restrict__ Bw,
                                                  const float* __restrict__ bias,
                                                  const float2* __restrict__ tab,
                                                  bf16_t* __restrict__ q_out,
                                                  bf16_t* __restrict__ k_out,
                                                  bf16_t* __restrict__ vt_out) {
    __shared__ __align__(16) char smem[65536];   // loop: 2 x 24KB; epilogue: 8 x 8KB

    int tid = threadIdx.x;
    int lane = tid & 63, wid = tid >> 6;
    int wm = wid >> 2, wn = wid & 3;             // wave grid 2M x 4N (64x64 tiles)
    int lr = lane & 15, lk = lane >> 4;

    // XCD bijective chunking: 384 blocks = 8 XCD x 48
    int l = blockIdx.y * 12 + blockIdx.x;
    int u = (l & 7) * 48 + (l >> 3);
    int bx = u % 12;                             // n-tile (256 wide)
    int by = u / 12;                             // m-tile (128 tall)

    f32x4 acc[4][4];
    f32x4 z = {0.f, 0.f, 0.f, 0.f};
#pragma unroll
    for (int i = 0; i < 4; i++)
#pragma unroll
        for (int j = 0; j < 4; j++) acc[i][j] = z;

    // ---- staging: swizzle on global source, LDS dest linear (G21) ----
    int cb = (tid & 3) * 16;                     // in-row byte (64B rows, BK=32)
    int rT = tid >> 2;                           // 0..127
    int sw = cb ^ (((rT >> 1) & 3) << 4);        // involution
    const char* gAp  = (const char*)A  + ((size_t)(by * 128 + rT)) * 2048 + sw;
    const char* gBp0 = (const char*)Bw + ((size_t)(bx * 256 + rT)) * 2048 + sw;
    const char* gBp1 = (const char*)Bw + ((size_t)(bx * 256 + 128 + rT)) * 2048 + sw;

    auto stg = [&](int par, int kt) __attribute__((always_inline)) {
        char* base = smem + par * 24576;
        gld16(gAp  + kt * 64, base + tid * 16);           // A [128][32]
        gld16(gBp0 + kt * 64, base + 8192 + tid * 16);    // B rows 0..127
        gld16(gBp1 + kt * 64, base + 16384 + tid * 16);   // B rows 128..255
    };

    // ---- fragment read offsets (same swizzle) ----
    int offA[4], offB[4];
#pragma unroll
    for (int m = 0; m < 4; m++) {
        int row = wm * 64 + m * 16 + lr;
        offA[m] = row * 64 + ((lk * 16) ^ (((row >> 1) & 3) << 4));
    }
#pragma unroll
    for (int n = 0; n < 4; n++) {
        int row = wn * 64 + n * 16 + lr;
        offB[n] = 8192 + row * 64 + ((lk * 16) ^ (((row >> 1) & 3) << 4));
    }

    stg(0, 0);
    for (int kt = 0; kt < 32; ++kt) {
        const char* buf = smem + (kt & 1) * 24576;
        WAITALL();                 // tile kt landed; own ds_reads of kt-1 done
        BARRIER();                 // all waves agree -> parity (kt+1)&1 free
        if (kt < 31) stg((kt + 1) & 1, kt + 1);
        bf16x8 Af[4], Bf[4];
#pragma unroll
        for (int m = 0; m < 4; m++) Af[m] = *(const bf16x8*)(buf + offA[m]);
#pragma unroll
        for (int n = 0; n < 4; n++) Bf[n] = *(const bf16x8*)(buf + offB[n]);
        __builtin_amdgcn_s_setprio(1);
#pragma unroll
        for (int m = 0; m < 4; m++)
#pragma unroll
            for (int n = 0; n < 4; n++)
                acc[m][n] = __builtin_amdgcn_mfma_f32_16x16x32_bf16(Af[m], Bf[n], acc[m][n], 0, 0, 0);
        __builtin_amdgcn_s_setprio(0);
    }
    WAITALL();
    BARRIER();   // all compute done before smem repurposed

    // ---- epilogue: per-wave 64x64 tile via wave-private 8KB LDS ----
    int m_base = by * 128 + wm * 64;
    int n_base = bx * 256 + wn * 64;
    char* myL = smem + wid * 8192;
    int which = n_base >> 10;               // 0=q 1=k 2=v (uniform per wave)
    int h = (n_base & 1023) >> 6;
    int b = m_base >> 11, t0 = m_base & 2047;
    int bh = b * H_ + h;
    if (which == 2) {
        // stage C^T: row=dh(64), col=t(64), t sigma^-1-permuted in 32-blocks
#pragma unroll
        for (int m = 0; m < 4; m++)
#pragma unroll
            for (int n = 0; n < 4; n++) {
                int rd = n * 16 + lr;
                float bv = bias[n_base + rd];
#pragma unroll
                for (int j = 0; j < 4; j++) {
                    int ct = m * 16 + lk * 4 + j;
                    int ct2 = (ct & 32) | (((ct >> 2) & 3) << 3) | (((ct >> 4) & 1) << 2) | (ct & 3);
                    int addr = (rd * 128 + ct2 * 2) ^ ((rd & 7) << 4);
                    *(bf16_t*)(myL + addr) = (bf16_t)(acc[m][n][j] + bv);
                }
            }
#pragma unroll
        for (int it = 0; it < 8; it++) {
            int row = it * 8 + (lane >> 3);     // dh
            int byt = (lane & 7) * 16;
            bf16x8 val = *(const bf16x8*)(myL + ((row * 128 + byt) ^ ((row & 7) << 4)));
            *(bf16x8*)(vt_out + ((size_t)bh * DH_ + row) * T_ + t0 + (lane & 7) * 8) = val;
        }
    } else {
        bf16_t* dst = which ? k_out : q_out;
        float qscl = which ? 1.0f : 0.18033688011112042f;  // q: fold (1/8)*log2(e)
#pragma unroll
        for (int m = 0; m < 4; m++)
#pragma unroll
            for (int n = 0; n < 4; n++) {
                int dh = n * 16 + lr;
                float bv = bias[n_base + dh];
                int dh2 = dh >> 1;
                bool even = (dh & 1) == 0;
#pragma unroll
                for (int j = 0; j < 4; j++) {
                    int rt = m * 16 + lk * 4 + j;
                    float v = acc[m][n][j] + bv;
                    float pp = __shfl_xor(v, 1);           // partner dh^1 in lane^1
                    float2 cs = tab[(t0 + rt) * 32 + dh2];
                    float r = even ? v * cs.x - pp * cs.y : v * cs.x + pp * cs.y;
                    r *= qscl;
                    int addr = (rt * 128 + dh * 2) ^ ((rt & 7) << 4);
                    *(bf16_t*)(myL + addr) = (bf16_t)r;
                }
            }
#pragma unroll
        for (int it = 0; it < 8; it++) {
            int row = it * 8 + (lane >> 3);     // t_local
            int byt = (lane & 7) * 16;
            bf16x8 val = *(const bf16x8*)(myL + ((row * 128 + byt) ^ ((row & 7) << 4)));
            *(bf16x8*)(dst + ((size_t)bh * T_ + t0 + row) * DH_ + (lane & 7) * 8) = val;
        }
    }
}

// ---------------- 128x128 GEMM (out-proj), 3-deep counted-vmcnt pipeline -----
__global__ __launch_bounds__(256) void gemm128o(const bf16_t* __restrict__ A,
                                                const bf16_t* __restrict__ Bw,
                                                const float* __restrict__ bias,
                                                float* __restrict__ f_out,
                                                int K, int N) {
    __shared__ __align__(16) char smem[49152];
    char* b0 = smem;
    char* b1 = smem + 16384;
    char* b2 = smem + 32768;

    int tid = threadIdx.x;
    int lane = tid & 63, wid = tid >> 6;
    int wr = wid >> 1, wc = wid & 1;
    int lr = lane & 15, lk = lane >> 4;

    int l = blockIdx.y * gridDim.x + blockIdx.x;
    int chunk = (gridDim.x * gridDim.y) >> 3;
    int u = (l & 7) * chunk + (l >> 3);
    int bx = u % gridDim.x;
    int by = u / gridDim.x;

    f32x4 acc[4][4];
    f32x4 z = {0.f, 0.f, 0.f, 0.f};
#pragma unroll
    for (int i = 0; i < 4; i++)
#pragma unroll
        for (int j = 0; j < 4; j++) acc[i][j] = z;

    const char* Ab = (const char*)(A + (size_t)by * 128 * K);
    const char* Bb = (const char*)(Bw + (size_t)bx * 128 * K);
    const int rowstride = K * 2;

    int p0 = tid * 16;
    int p1 = 4096 + tid * 16;
    int r0 = p0 >> 6, r1 = p1 >> 6;
    int cb0 = (p0 & 63) ^ (((r0 >> 1) & 3) << 4);
    int cb1 = (p1 & 63) ^ (((r1 >> 1) & 3) << 4);
    size_t gA0 = (size_t)r0 * rowstride + cb0;
    size_t gA1 = (size_t)r1 * rowstride + cb1;

    int oa[4], ob[4];
#pragma unroll
    for (int m = 0; m < 4; m++) {
        int row = wr * 64 + m * 16 + lr;
        oa[m] = row * 64 + ((lk * 16) ^ (((row >> 1) & 3) << 4));
    }
#pragma unroll
    for (int n = 0; n < 4; n++) {
        int row = wc * 64 + n * 16 + lr;
        ob[n] = row * 64 + ((lk * 16) ^ (((row >> 1) & 3) << 4));
    }

    auto stg = [&](char* buf, int ks) __attribute__((always_inline)) {
        const char* Ag = Ab + (size_t)ks * 64;
        const char* Bg = Bb + (size_t)ks * 64;
        gld16(Ag + gA0, buf + p0);
        gld16(Ag + gA1, buf + p1);
        gld16(Bg + gA0, buf + 8192 + p0);
        gld16(Bg + gA1, buf + 8192 + p1);
    };

    auto iterf = [&](auto vmc, char* buf, int ks, bool dostage) __attribute__((always_inline)) {
        constexpr int VM = decltype(vmc)::value;
        if constexpr (VM == 8)      asm volatile("s_waitcnt vmcnt(8)" ::: "memory");
        else if constexpr (VM == 4) asm volatile("s_waitcnt vmcnt(4)" ::: "memory");
        else                        asm volatile("s_waitcnt vmcnt(0)" ::: "memory");
        __builtin_amdgcn_s_barrier();
        asm volatile("" ::: "memory");
        bf16x8 Af[4], Bf[4];
#pragma unroll
        for (int m = 0; m < 4; m++) Af[m] = *(const bf16x8*)(buf + oa[m]);
#pragma unroll
        for (int n = 0; n < 4; n++) Bf[n] = *(const bf16x8*)(buf + 8192 + ob[n]);
#pragma unroll
        for (int m = 0; m < 4; m++)
#pragma unroll
            for (int n = 0; n < 4; n++)
                acc[m][n] = __builtin_amdgcn_mfma_f32_16x16x32_bf16(Af[m], Bf[n], acc[m][n], 0, 0, 0);
        asm volatile("" ::: "memory");
        __builtin_amdgcn_s_barrier();
        asm volatile("" ::: "memory");
        if (dostage) stg(buf, ks);
    };

    std::integral_constant<int, 8> c8;
    std::integral_constant<int, 4> c4;
    std::integral_constant<int, 0> c0;

    stg(b0, 0);
    stg(b1, 1);
    stg(b2, 2);
    for (int s = 0; s < 30; s += 3) {
        iterf(c8, b0, s + 3, s + 3 < 32);
        iterf(c8, b1, s + 4, s + 4 < 32);
        iterf(c8, b2, s + 5, s + 5 < 32);
    }
    iterf(c4, b0, 0, false);
    iterf(c0, b1, 0, false);

    int m_base = by * 128 + wr * 64;
    int n_base = bx * 128 + wc * 64;
#pragma unroll
    for (int m = 0; m < 4; m++) {
        int gm0 = m_base + m * 16 + lk * 4;
#pragma unroll
        for (int n = 0; n < 4; n++) {
            int nc = n_base + n * 16 + lr;
            float bv = bias[nc];
#pragma unroll
            for (int j = 0; j < 4; j++)
                f_out[(size_t)(gm0 + j) * N + nc] = acc[m][n][j] + bv;
        }
    }
}

// ------- flash attention: 128 q/block + T15 double-P pipeline ----------------
// r9 structure (best measured 50 us) + two P register sets alternated
// statically: QK(s+1)->Pnew is independent of PV(s)<-Pold, and the kt/dt
// loops are fused so exp2 VALU overlaps PV MFMA in the scheduler window.
__global__ __launch_bounds__(256, 4) void attn128(const bf16_t* __restrict__ Q,
                                                  const bf16_t* __restrict__ K,
                                                  const bf16_t* __restrict__ Vt,
                                                  bf16_t* __restrict__ Ao) {
    __shared__ __align__(16) char smem[40960];  // K0@0 K1@8K V0@16K V1@24K V2@32K

    int tid = threadIdx.x;
    int lane = tid & 63, wid = tid >> 6;
    int lr = lane & 15, lk = lane >> 4;
    int xcd = blockIdx.x & 7, idx = blockIdx.x >> 3;
    int bh = xcd * 4 + (idx & 3);
    int i4 = idx >> 2;                 // 0..15
    int qt = (i4 < 8) ? i4 : 23 - i4;  // pairs sum to 15 -> per-CU work constant
    int q0 = qt * 128;
    int qrelw = wid * 16 + lr;         // q row within its group

    const bf16_t* Qp0 = Q + ((size_t)bh * T_ + q0 + qrelw) * DH_;
    const bf16_t* Qp1 = Qp0 + 64 * DH_;
    bf16x8 qa0 = *(const bf16x8*)(Qp0 + lk * 8);       // group0
    bf16x8 qa1 = *(const bf16x8*)(Qp0 + 32 + lk * 8);
    bf16x8 qb0 = *(const bf16x8*)(Qp1 + lk * 8);       // group1
    bf16x8 qb1 = *(const bf16x8*)(Qp1 + 32 + lk * 8);

    f32x4 zz = {0.f, 0.f, 0.f, 0.f};
    f32x4 oa0[4], oa1[4];              // O^T per group: col q=lr, rows dh
#pragma unroll
    for (int dt = 0; dt < 4; dt++) { oa0[dt] = zz; oa1[dt] = zz; }
    float ls0 = 0.f, ls1 = 0.f;        // per-lane partial row-sums
    // two P sets (T15): set0 and set1, statically alternated
    bf16x8 PA0_0, PA1_0, PB0_0, PB1_0;
    bf16x8 PA0_1, PA1_1, PB0_1, PB1_1;

    const char* Kbase = (const char*)(K + (size_t)bh * T_ * DH_);
    const char* Vbase = (const char*)(Vt + (size_t)bh * DH_ * T_);

    char* Kr = smem + 8192;            // K(s+1)
    char* Kw = smem;
    char* Vr = smem + 16384;           // V(s)
    char* Vn = smem + 24576;           // V(s+1)
    char* Vw = smem + 32768;

    auto stage = [&](int s, char* Kd, char* Vd) __attribute__((always_inline)) {
        int kv0 = s * 64;
        const char* Kg = Kbase + (size_t)kv0 * 128;
#pragma unroll
        for (int c = 0; c < 2; c++) {
            int o = c * 4096 + tid * 16;
            int r = o >> 7;
            int g = o ^ ((r & 7) << 4);               // pre-swizzled source
            gld16(Kg + g, Kd + o);
            gld16(Vbase + (size_t)r * (T_ * 2) + kv0 * 2 + (g & 127), Vd + o);
        }
    };

    // plain QK (prologue only), writes dest set
    auto do_qk = [&](const char* Kc, int m0, int m1,
                     bf16x8& wA0, bf16x8& wA1, bf16x8& wB0, bf16x8& wB1)
                 __attribute__((always_inline)) {
#pragma unroll
        for (int kt = 0; kt < 4; kt++) {
            int row = kt * 16 + lr;
            int key = (row & 7) << 4;
            bf16x8 kf0 = *(const bf16x8*)(Kc + ((row * 128 + lk * 16) ^ key));
            bf16x8 kf1 = *(const bf16x8*)(Kc + ((row * 128 + 64 + lk * 16) ^ key));
            {
                f32x4 s = zz;
                s = __builtin_amdgcn_mfma_f32_16x16x32_bf16(kf0, qa0, s, 0, 0, 0);
                s = __builtin_amdgcn_mfma_f32_16x16x32_bf16(kf1, qa1, s, 0, 0, 0);
#pragma unroll
                for (int j = 0; j < 4; j++) {
                    float sv = s[j];
                    if (m0 == 1) {
                        int kv = kt * 16 + lk * 4 + j;
                        sv = (kv <= qrelw) ? sv : -__builtin_inff();
                    }
                    float e = exp2f(sv);
                    ls0 += e;
                    if (kt < 2) wA0[kt * 4 + j] = (bf16_t)e;
                    else        wA1[(kt - 2) * 4 + j] = (bf16_t)e;
                }
            }
            {
                f32x4 s = zz;
                s = __builtin_amdgcn_mfma_f32_16x16x32_bf16(kf0, qb0, s, 0, 0, 0);
                s = __builtin_amdgcn_mfma_f32_16x16x32_bf16(kf1, qb1, s, 0, 0, 0);
#pragma unroll
                for (int j = 0; j < 4; j++) {
                    float sv = s[j];
                    if (m1 == 1) {
                        int kv = kt * 16 + lk * 4 + j;
                        sv = (kv <= qrelw) ? sv : -__builtin_inff();
                    }
                    float e = exp2f(sv);
                    ls1 += e;
                    if (kt < 2) wB0[kt * 4 + j] = (bf16_t)e;
                    else        wB1[(kt - 2) * 4 + j] = (bf16_t)e;
                }
            }
        }
    };

    int last = 2 * qt;                 // tiles 0..2qt+1; iters s=0..last

    // fused iter: PV(s) from P-old (read refs) || QK(s+1) into P-new (write refs)
    auto iterX = [&](int s, int m0, int m1,
                     bf16x8& rA0, bf16x8& rA1, bf16x8& rB0, bf16x8& rB1,
                     bf16x8& wA0, bf16x8& wA1, bf16x8& wB0, bf16x8& wB1)
                 __attribute__((always_inline)) {
        WAITALL();                     // tile s+1 landed; own reads of s-1 done
        __builtin_amdgcn_s_barrier();
        asm volatile("" ::: "memory");
        if (s + 2 <= last + 1) stage(s + 2, Kw, Vw);
#pragma unroll
        for (int i = 0; i < 4; i++) {
            int row = i * 16 + lr;
            int key = (row & 7) << 4;
            // ---- QK part (kt = i), tile s+1, writes P-new ----
            bf16x8 kf0 = *(const bf16x8*)(Kr + ((row * 128 + lk * 16) ^ key));
            bf16x8 kf1 = *(const bf16x8*)(Kr + ((row * 128 + 64 + lk * 16) ^ key));
            if (m0 != 2) {
                f32x4 s_ = zz;
                s_ = __builtin_amdgcn_mfma_f32_16x16x32_bf16(kf0, qa0, s_, 0, 0, 0);
                s_ = __builtin_amdgcn_mfma_f32_16x16x32_bf16(kf1, qa1, s_, 0, 0, 0);
#pragma unroll
                for (int j = 0; j < 4; j++) {
                    float sv = s_[j];
                    if (m0 == 1) {
                        int kv = i * 16 + lk * 4 + j;
                        sv = (kv <= qrelw) ? sv : -__builtin_inff();
                    }
                    float e = exp2f(sv);
                    ls0 += e;
                    if (i < 2) wA0[i * 4 + j] = (bf16_t)e;
                    else       wA1[(i - 2) * 4 + j] = (bf16_t)e;
                }
            }
            {
                f32x4 s_ = zz;
                s_ = __builtin_amdgcn_mfma_f32_16x16x32_bf16(kf0, qb0, s_, 0, 0, 0);
                s_ = __builtin_amdgcn_mfma_f32_16x16x32_bf16(kf1, qb1, s_, 0, 0, 0);
#pragma unroll
                for (int j = 0; j < 4; j++) {
                    float sv = s_[j];
                    if (m1 == 1) {
                        int kv = i * 16 + lk * 4 + j;
                        sv = (kv <= qrelw) ? sv : -__builtin_inff();
                    }
                    float e = exp2f(sv);
                    ls1 += e;
                    if (i < 2) wB0[i * 4 + j] = (bf16_t)e;
                    else       wB1[(i - 2) * 4 + j] = (bf16_t)e;
                }
            }
            // ---- PV part (dt = i), tile s, reads P-old (independent of QK) ----
            bf16x8 vf0 = *(const bf16x8*)(Vr + ((row * 128 + lk * 16) ^ key));
            bf16x8 vf1 = *(const bf16x8*)(Vr + ((row * 128 + 64 + lk * 16) ^ key));
            f32x4 a = oa0[i];
            a = __builtin_amdgcn_mfma_f32_16x16x32_bf16(vf0, rA0, a, 0, 0, 0);
            a = __builtin_amdgcn_mfma_f32_16x16x32_bf16(vf1, rA1, a, 0, 0, 0);
            oa0[i] = a;
            f32x4 b = oa1[i];
            b = __builtin_amdgcn_mfma_f32_16x16x32_bf16(vf0, rB0, b, 0, 0, 0);
            b = __builtin_amdgcn_mfma_f32_16x16x32_bf16(vf1, rB1, b, 0, 0, 0);
            oa1[i] = b;
        }
        char* t = Kr; Kr = Kw; Kw = t;
        t = Vr; Vr = Vn; Vn = Vw; Vw = t;
    };

    // ---- prologue: tiles 0,1 staged; QK(0) -> P set0 ----
    stage(0, Kw, Vr);                  // K0 into Kw(=smem), V0 into Vr
    stage(1, Kr, Vn);                  // K1, V1
    asm volatile("s_waitcnt vmcnt(4)" ::: "memory");   // tile 0 landed
    __builtin_amdgcn_s_barrier();
    asm volatile("" ::: "memory");
    do_qk(Kw, qt == 0 ? 1 : 0, 0, PA0_0, PA1_0, PB0_0, PB1_0);

    // ---- pairs: s even reads set0/writes set1; s+1 reads set1/writes set0 ----
    for (int s = 0; s < last; s += 2) {
        iterX(s,     0, 0,
              PA0_0, PA1_0, PB0_0, PB1_0, PA0_1, PA1_1, PB0_1, PB1_1);
        iterX(s + 1, (s + 1 == last - 1) ? 1 : 0, 0,
              PA0_1, PA1_1, PB0_1, PB1_1, PA0_0, PA1_0, PB0_0, PB1_0);
    }
    // ---- tail: s = last (even) reads set0, QK(last+1) masks (2,1) -> set1 ----
    iterX(last, 2, 1,
          PA0_0, PA1_0, PB0_0, PB1_0, PA0_1, PA1_1, PB0_1, PB1_1);
    {   // final PV (tile last+1), group1 only, P = set1
#pragma unroll
        for (int dt = 0; dt < 4; dt++) {
            int row = dt * 16 + lr;
            int key = (row & 7) << 4;
            bf16x8 vf0 = *(const bf16x8*)(Vr + ((row * 128 + lk * 16) ^ key));
            bf16x8 vf1 = *(const bf16x8*)(Vr + ((row * 128 + 64 + lk * 16) ^ key));
            f32x4 o = oa1[dt];
            o = __builtin_amdgcn_mfma_f32_16x16x32_bf16(vf0, PB0_1, o, 0, 0, 0);
            o = __builtin_amdgcn_mfma_f32_16x16x32_bf16(vf1, PB1_1, o, 0, 0, 0);
            oa1[dt] = o;
        }
    }
    __syncthreads();                    // smem about to be repurposed

    ls0 += __shfl_xor(ls0, 16); ls0 += __shfl_xor(ls0, 32);
    ls1 += __shfl_xor(ls1, 16); ls1 += __shfl_xor(ls1, 32);
    float ri0 = __builtin_amdgcn_rcpf(ls0);
    float ri1 = __builtin_amdgcn_rcpf(ls1);

    char* myL = smem + wid * 2048;
    int b = bh >> 4, h = bh & 15;
#pragma unroll
    for (int dt = 0; dt < 4; dt++)
#pragma unroll
        for (int j = 0; j < 4; j++) {
            int dh = dt * 16 + lk * 4 + j;
            int addr = (lr * 128 + dh * 2) ^ ((lr & 7) << 4);
            *(bf16_t*)(myL + addr) = (bf16_t)(oa0[dt][j] * ri0);
        }
#pragma unroll
    for (int it = 0; it < 2; it++) {
        int row = it * 8 + (lane >> 3);
        int byt = (lane & 7) * 16;
        bf16x8 val = *(const bf16x8*)(myL + ((row * 128 + byt) ^ ((row & 7) << 4)));
        int t = q0 + wid * 16 + row;
        *(bf16x8*)(Ao + ((size_t)b * T_ + t) * D_ + h * DH_ + (lane & 7) * 8) = val;
    }
#pragma unroll
    for (int dt = 0; dt < 4; dt++)
#pragma unroll
        for (int j = 0; j < 4; j++) {
            int dh = dt * 16 + lk * 4 + j;
            int addr = (lr * 128 + dh * 2) ^ ((lr & 7) << 4);
            *(bf16_t*)(myL + addr) = (bf16_t)(oa1[dt][j] * ri1);
        }
#pragma unroll
    for (int it = 0; it < 2; it++) {
        int row = it * 8 + (lane >> 3);
        int byt = (lane & 7) * 16;
        bf16x8 val = *(const bf16x8*)(myL + ((row * 128 + byt) ^ ((row & 7) << 4)));
        int t = q0 + 64 + wid * 16 + row;
        *(bf16x8*)(Ao + ((size_t)b * T_ + t) * D_ + h * DH_ + (lane & 7) * 8) = val;
    }
}

// ---------------- launch ----------------
extern "C" void kernel_launch(void* const* d_in, const int* in_sizes, int n_in,
                              void* d_out, int out_size, void* d_ws, size_t ws_size,
                              hipStream_t stream) {
    const float* x     = (const float*)d_in[0];
    const float* w_qkv = (const float*)d_in[1];
    const float* b_qkv = (const float*)d_in[2];
    const float* w_out = (const float*)d_in[3];
    const float* b_out = (const float*)d_in[4];
    float* out = (float*)d_out;

    char* ws = (char*)d_ws;
    bf16_t* xb    = (bf16_t*)(ws);               //  8 MB  [4096][1024]
    bf16_t* wqkvb = (bf16_t*)(ws + 8388608);     //  6 MB  [3072][1024]
    bf16_t* wob   = (bf16_t*)(ws + 14680064);    //  2 MB  [1024][1024]
    bf16_t* qb    = (bf16_t*)(ws + 16777216);    //  8 MB  [32][2048][64] (pre-scaled)
    bf16_t* kb    = (bf16_t*)(ws + 25165824);    //  8 MB  [32][2048][64]
    bf16_t* vtb   = (bf16_t*)(ws + 33554432);    //  8 MB  [32][64][2048] (sigma-permuted t)
    bf16_t* ab    = (bf16_t*)(ws + 41943040);    //  8 MB  [4096][1024]
    float2* tab   = (float2*)(ws + 41943040);    // 512 KB RoPE table, lives in ab region

    cvt3<<<8448, 256, 0, stream>>>(x, w_qkv, w_out, xb, wqkvb, wob, tab);

    gemmqkv<<<dim3(12, 32), 512, 0, stream>>>(xb, wqkvb, b_qkv, tab, qb, kb, vtb);
    attn128<<<512, 256, 0, stream>>>(qb, kb, vtb, ab);
    gemm128o<<<dim3(8, 32), 256, 0, stream>>>(ab, wob, b_out, out, 1024, 1024);
}